// Round 3
// baseline (55213.666 us; speedup 1.0000x reference)
//
#include <hip/hip_runtime.h>
#include <hip/hip_cooperative_groups.h>
#include <math.h>

namespace cg = cooperative_groups;

constexpr int kB = 64, kS = 24, kT = 96, kE = 256, kH = 512, kA = 512;
constexpr int NWG = 256, NTH = 512;

// ws layout (floats)
constexpr int OFF_H   = 0;                          // 2*kB*kH word h (double buf)
constexpr int OFF_SH  = OFF_H + 2 * kB * kH;        // 2*kB*kH sent h (double buf)
constexpr int OFF_HS  = OFF_SH + 2 * kB * kH;       // kB*kT*kH word_hs
constexpr int OFF_Z   = OFF_HS + kB * kT * kH;      // kB*kT
constexpr int OFF_CTX = OFF_Z + kB * kT;            // kB*kH
constexpr int OFF_SHS = OFF_CTX + kB * kH;          // kB*kS*kH
constexpr int OFF_Z2  = OFF_SHS + kB * kS * kH;     // kB*kS
constexpr int OFF_BAR = (OFF_Z2 + kB * kS + 31) & ~31;  // 3 streams x 1024 u32

__device__ __forceinline__ float sigmoidf(float x) { return 1.0f / (1.0f + expf(-x)); }
__device__ __forceinline__ float dot4(float4 a, float4 b) {
  return a.x * b.x + a.y * b.y + a.z * b.z + a.w * b.w;
}

// Coherent (LLC) data access: relaxed agent-scope atomics -> sc0/sc1 loads/stores,
// bypass non-coherent L1/L2. No fences needed for data published this way.
__device__ __forceinline__ float2 aload2(const float* p) {
  unsigned long long u = __hip_atomic_load((const unsigned long long*)p,
                                           __ATOMIC_RELAXED, __HIP_MEMORY_SCOPE_AGENT);
  union { unsigned long long u; float2 f; } cv; cv.u = u;
  return cv.f;
}
__device__ __forceinline__ float aload1(const float* p) {
  return __hip_atomic_load(p, __ATOMIC_RELAXED, __HIP_MEMORY_SCOPE_AGENT);
}
__device__ __forceinline__ void astore(float* p, float v) {
  __hip_atomic_store(p, v, __ATOMIC_RELAXED, __HIP_MEMORY_SCOPE_AGENT);
}

// Cheap 2-level split-phase barrier (16 groups x 16 WGs). Monotonic counters.
// bar points at this stream's region: [grp*32] counters, [512] root.
__device__ __forceinline__ void bar_arrive(unsigned* bar, int n, int g, int tid) {
  __syncthreads();  // per-wave vmcnt(0) drain: our coherent stores are visible
  if (tid == 0) {
    unsigned old = __hip_atomic_fetch_add(&bar[(g & 15) * 32], 1u,
                                          __ATOMIC_RELEASE, __HIP_MEMORY_SCOPE_AGENT);
    if (old == (unsigned)(16 * n - 1))
      __hip_atomic_fetch_add(&bar[512], 1u, __ATOMIC_RELEASE, __HIP_MEMORY_SCOPE_AGENT);
  }
}
__device__ __forceinline__ void bar_wait(unsigned* bar, int n, int tid) {
  if (tid == 0) {
    while (__hip_atomic_load(&bar[512], __ATOMIC_RELAXED, __HIP_MEMORY_SCOPE_AGENT) <
           (unsigned)(16 * n))
      __builtin_amdgcn_s_sleep(1);
  }
  __syncthreads();
}

__global__ __launch_bounds__(NTH) void ha_kernel(
    const int* __restrict__ captions, const int* __restrict__ masks,
    const float* __restrict__ embed_W,
    const float* __restrict__ w_Wih, const float* __restrict__ w_Whh,
    const float* __restrict__ w_bih, const float* __restrict__ w_bhh,
    const float* __restrict__ s_Wih, const float* __restrict__ s_Whh,
    const float* __restrict__ s_bih, const float* __restrict__ s_bhh,
    const float* __restrict__ wa_Wk, const float* __restrict__ wa_Wv,
    const float* __restrict__ sa_Wk, const float* __restrict__ sa_Wv,
    float* __restrict__ out, float* __restrict__ ws) {
  cg::grid_group grid = cg::this_grid();
  const int g = blockIdx.x, tid = threadIdx.x;
  const int jj = tid & 15, bb2 = tid >> 4;   // word phase: 16-way K-split x 32 batch
  const int jj8 = tid & 7, bb8 = tid >> 3;   // sentence phase: 8-way K-split x 64 batch

  float* h_buf = ws + OFF_H;
  float* sh_buf = ws + OFF_SH;
  float* hs_buf = ws + OFF_HS;
  float* z_buf = ws + OFF_Z;
  float* ctx_ws = ws + OFF_CTX;
  float* sent_hs = ws + OFF_SHS;
  float* z2_buf = ws + OFF_Z2;
  unsigned* barA = (unsigned*)(ws + OFF_BAR);
  unsigned* barB = barA + 1024;
  unsigned* barC = barA + 2048;

  // LDS ~52 KB
  __shared__ __align__(16) float wih_s[8][260];
  __shared__ __align__(16) float whh_s[8][516];
  __shared__ float bias_s[8];
  __shared__ __align__(16) float smem_u[6192];  // hpart | hpart2 | attn_f (aliased)
  __shared__ float c_s[2][kB], hown_s[2][kB], sc_s[2][kB];
  __shared__ float soft_s[kT], red_s[96];

  float (*hpart)[32][18] = reinterpret_cast<float (*)[32][18]>(&smem_u[0]);   // 4608 f
  float (*hpart2)[64][10] = reinterpret_cast<float (*)[64][10]>(&smem_u[0]);  // 5120 f
  float* attn_f = &smem_u[0];                                                 // 12x516

  // ---- init ----
  for (int idx = tid; idx < 8 * kE; idx += NTH) {
    int c = idx >> 8, e = idx & (kE - 1);
    wih_s[c][e] = w_Wih[((c >> 1) * kH + 2 * g + (c & 1)) * kE + e];
  }
  for (int idx = tid; idx < 8 * kH; idx += NTH) {
    int c = idx >> 9, k = idx & (kH - 1);
    whh_s[c][k] = w_Whh[((c >> 1) * kH + 2 * g + (c & 1)) * kH + k];
  }
  if (tid < 8) {
    int row = (tid >> 1) * kH + 2 * g + (tid & 1);
    bias_s[tid] = w_bih[row] + w_bhh[row];
  }
  if (tid < kB) {
    c_s[0][tid] = 0.f; c_s[1][tid] = 0.f;
    hown_s[0][tid] = 0.f; hown_s[1][tid] = 0.f;
    sc_s[0][tid] = 0.f; sc_s[1][tid] = 0.f;
  }
  {
    int idx = g * NTH + tid;  // 131072 threads == 2*(2*kB*kH)
    if (idx < 2 * kB * kH) h_buf[idx] = 0.f;
    else sh_buf[idx - 2 * kB * kH] = 0.f;
  }
  if (g == 0)
    for (int idx = tid; idx < 3 * 1024; idx += NTH) barA[idx] = 0u;
  grid.sync();  // heavy fence: publishes zeros + counters to LLC

  float xA[8], xB[8];  // x@Wih^T register partials (prefetched one step ahead)

  auto prefetch = [&](int chunk, int s2, int t2, float* xacc) {
    const int b = chunk * 32 + bb2;
    const int cap = captions[(b * kS + s2) * kT + t2];
    const float4* __restrict__ xrow = (const float4*)(embed_W + (size_t)cap * kE);
#pragma unroll
    for (int c = 0; c < 8; ++c) xacc[c] = 0.f;
#pragma unroll
    for (int i = 0; i < 4; ++i) {
      const int ch = jj + 16 * i;
      float4 xv = xrow[ch];
#pragma unroll
      for (int c = 0; c < 8; ++c)
        xacc[c] += dot4(*(const float4*)&wih_s[c][4 * ch], xv);
    }
  };

  prefetch(0, 0, 0, xA);
  prefetch(1, 0, 0, xB);

  int nA = 0, nB = 0, nC = 0, gstep = 0;
  for (int s = 0; s < kS; ++s) {
    // ================= word LSTM: 96 steps, 2-chunk pipelined =================
    for (int t = 0; t < kT; ++t, ++gstep) {
      const float* hcur = h_buf + (gstep & 1) * kB * kH;
      float* hnxt = h_buf + ((gstep + 1) & 1) * kB * kH;

      for (int chunk = 0; chunk < 2; ++chunk) {
        const float* xacc = chunk ? xB : xA;
        // dots: thread (jj,bb2) covers k-chunks {jj+16i}, all 8 owned gate cols
        {
          const float* __restrict__ hrow = hcur + (chunk * 32 + bb2) * kH;
          float acc[8];
#pragma unroll
          for (int c = 0; c < 8; ++c) acc[c] = xacc[c];
#pragma unroll
          for (int i = 0; i < 8; ++i) {
            const int ch = jj + 16 * i;
            float2 p0 = aload2(hrow + 4 * ch);
            float2 p1 = aload2(hrow + 4 * ch + 2);
#pragma unroll
            for (int c = 0; c < 8; ++c) {
              const float4 w = *(const float4*)&whh_s[c][4 * ch];
              acc[c] += w.x * p0.x + w.y * p0.y + w.z * p1.x + w.w * p1.y;
            }
          }
#pragma unroll
          for (int c = 0; c < 8; ++c) hpart[c][bb2][jj] = acc[c];
        }
        __syncthreads();
        // assemble: gates -> nonlinearity -> masked state update -> publish
        if (tid < 64) {
          const int p = tid & 1, b2 = tid >> 1, b = chunk * 32 + b2;
          float gate[4];
#pragma unroll
          for (int q = 0; q < 4; ++q) {
            const int c = 2 * q + p;
            float sum = bias_s[c];
            const float2* row = (const float2*)&hpart[c][b2][0];
#pragma unroll
            for (int u = 0; u < 8; ++u) { float2 v = row[u]; sum += v.x + v.y; }
            gate[q] = sum;
          }
          float cold = c_s[p][b];
          float c2 = sigmoidf(gate[1]) * cold + sigmoidf(gate[0]) * tanhf(gate[2]);
          float h2 = sigmoidf(gate[3]) * tanhf(c2);
          const int m = masks[(b * kS + s) * kT + t];
          float cn = m ? c2 : cold;
          float hn = m ? h2 : hown_s[p][b];
          c_s[p][b] = cn;
          hown_s[p][b] = hn;
          const int col = 2 * g + p;
          astore(&hnxt[b * kH + col], hn);
          astore(&hs_buf[(b * kT + t) * kH + col], m ? h2 : 0.f);
        }
        if (chunk == 0) {
          ++nA; bar_arrive(barA, nA, g, tid);
          if (t < kT - 1) prefetch(0, s, t + 1, xA);
          bar_wait(barB, nB, tid);          // hB(t-1) ready (no-op at t==0 of s==0)
        } else {
          ++nB; bar_arrive(barB, nB, g, tid);
          if (t < kT - 1) prefetch(1, s, t + 1, xB);
          bar_wait(barA, nA, tid);          // hA(t) ready for next iteration
        }
      }
    }
    bar_wait(barB, nB, tid);  // hB/hs of t=kT-1 published

    // ================= word attention: z[b,t] =================
    {
      const int ab = g >> 2, at0 = (g & 3) * 24;
      for (int half = 0; half < 2; ++half) {
        const int tb = at0 + half * 12;
        for (int idx = tid; idx < 12 * 256; idx += NTH) {
          int pp = idx >> 8, hh2 = (idx & 255) * 2;
          float2 v = aload2(&hs_buf[(ab * kT + tb + pp) * kH + hh2]);
          *(float2*)&attn_f[pp * 516 + hh2] = v;
        }
        __syncthreads();
        const int aa = tid;  // NTH == kA
        float dacc[12];
#pragma unroll
        for (int p = 0; p < 12; ++p) dacc[p] = 0.f;
        const float4* __restrict__ wk = (const float4*)(wa_Wk + aa * kH);
        for (int k = 0; k < kH / 4; ++k) {
          float4 w = wk[k];
#pragma unroll
          for (int p = 0; p < 12; ++p)
            dacc[p] += dot4(w, *(const float4*)&attn_f[p * 516 + k * 4]);
        }
        const float wv = wa_Wv[aa];
        const int lane = tid & 63, wid = tid >> 6;
#pragma unroll
        for (int p = 0; p < 12; ++p) {
          float v = wv * tanhf(dacc[p]);
          v += __shfl_down(v, 32); v += __shfl_down(v, 16); v += __shfl_down(v, 8);
          v += __shfl_down(v, 4);  v += __shfl_down(v, 2);  v += __shfl_down(v, 1);
          if (lane == 0) red_s[wid * 12 + p] = v;
        }
        __syncthreads();
        if (tid < 12) {
          float sum = 0.f;
#pragma unroll
          for (int w = 0; w < 8; ++w) sum += red_s[w * 12 + tid];
          astore(&z_buf[ab * kT + tb + tid], sum);
        }
        __syncthreads();
      }
    }
    ++nC; bar_arrive(barC, nC, g, tid); bar_wait(barC, nC, tid);

    // ================= softmax over T + ctx =================
    if (g < kB) {
      const int b = g;
      if (tid < kT) soft_s[tid] = aload1(&z_buf[b * kT + tid]);
      __syncthreads();
      float mx = -1e30f;
      for (int i = 0; i < kT; ++i) mx = fmaxf(mx, soft_s[i]);
      float den = 0.f;
      for (int i = 0; i < kT; ++i) den += expf(soft_s[i] - mx);
      __syncthreads();
      if (tid < kT) soft_s[tid] = expf(soft_s[tid] - mx) / den;
      __syncthreads();
      {
        const int h0 = tid;  // NTH == kH
        float a0 = 0.f, a1 = 0.f, a2 = 0.f, a3 = 0.f;
        for (int tt = 0; tt < kT; tt += 4) {
          a0 += soft_s[tt + 0] * aload1(&hs_buf[(b * kT + tt + 0) * kH + h0]);
          a1 += soft_s[tt + 1] * aload1(&hs_buf[(b * kT + tt + 1) * kH + h0]);
          a2 += soft_s[tt + 2] * aload1(&hs_buf[(b * kT + tt + 2) * kH + h0]);
          a3 += soft_s[tt + 3] * aload1(&hs_buf[(b * kT + tt + 3) * kH + h0]);
        }
        astore(&ctx_ws[b * kH + h0], (a0 + a1) + (a2 + a3));
      }
    }
    ++nC; bar_arrive(barC, nC, g, tid); bar_wait(barC, nC, tid);

    // ================= sentence LSTM step =================
    {
      const float* shc = sh_buf + (s & 1) * kB * kH;
      float* shn = sh_buf + ((s + 1) & 1) * kB * kH;
      float acc[8];
#pragma unroll
      for (int c = 0; c < 8; ++c) acc[c] = 0.f;
      for (int i = 0; i < 16; ++i) {
        const int ch = jj8 + 8 * i;
        float2 x0 = aload2(ctx_ws + bb8 * kH + 4 * ch);
        float2 x1 = aload2(ctx_ws + bb8 * kH + 4 * ch + 2);
        float2 h0 = aload2(shc + bb8 * kH + 4 * ch);
        float2 h1 = aload2(shc + bb8 * kH + 4 * ch + 2);
#pragma unroll
        for (int c = 0; c < 8; ++c) {
          const int row = (c >> 1) * kH + 2 * g + (c & 1);
          float4 wi = *(const float4*)(s_Wih + row * kH + 4 * ch);
          float4 wh = *(const float4*)(s_Whh + row * kH + 4 * ch);
          acc[c] += wi.x * x0.x + wi.y * x0.y + wi.z * x1.x + wi.w * x1.y +
                    wh.x * h0.x + wh.y * h0.y + wh.z * h1.x + wh.w * h1.y;
        }
      }
#pragma unroll
      for (int c = 0; c < 8; ++c) hpart2[c][bb8][jj8] = acc[c];
      __syncthreads();
      if (tid < 128) {
        const int p = tid & 1, b = tid >> 1;
        float gate[4];
#pragma unroll
        for (int q = 0; q < 4; ++q) {
          const int c = 2 * q + p;
          const int row = q * kH + 2 * g + p;
          float sum = s_bih[row] + s_bhh[row];
          const float2* rp = (const float2*)&hpart2[c][b][0];
#pragma unroll
          for (int u = 0; u < 4; ++u) { float2 v = rp[u]; sum += v.x + v.y; }
          gate[q] = sum;
        }
        float c2 = sigmoidf(gate[1]) * sc_s[p][b] + sigmoidf(gate[0]) * tanhf(gate[2]);
        float h2 = sigmoidf(gate[3]) * tanhf(c2);
        sc_s[p][b] = c2;
        const int col = 2 * g + p;
        astore(&shn[b * kH + col], h2);
        astore(&sent_hs[(b * kS + s) * kH + col], h2);
      }
    }
    ++nC; bar_arrive(barC, nC, g, tid);
    if (s < kS - 1) { prefetch(0, s + 1, 0, xA); prefetch(1, s + 1, 0, xB); }
    bar_wait(barC, nC, tid);
  }

  // ================= final attention over S =================
  {
    const int pair0 = g * 6;  // 1536 (b,s) pairs / 256 WGs
    for (int idx = tid; idx < 6 * 256; idx += NTH) {
      int pp = idx >> 8, hh2 = (idx & 255) * 2;
      float2 v = aload2(&sent_hs[(pair0 + pp) * kH + hh2]);
      *(float2*)&attn_f[pp * 516 + hh2] = v;
    }
    __syncthreads();
    const int aa = tid;
    float dacc[6];
#pragma unroll
    for (int p = 0; p < 6; ++p) dacc[p] = 0.f;
    const float4* __restrict__ wk = (const float4*)(sa_Wk + aa * kH);
    for (int k = 0; k < kH / 4; ++k) {
      float4 w = wk[k];
#pragma unroll
      for (int p = 0; p < 6; ++p)
        dacc[p] += dot4(w, *(const float4*)&attn_f[p * 516 + k * 4]);
    }
    const float wv = sa_Wv[aa];
    const int lane = tid & 63, wid = tid >> 6;
#pragma unroll
    for (int p = 0; p < 6; ++p) {
      float v = wv * tanhf(dacc[p]);
      v += __shfl_down(v, 32); v += __shfl_down(v, 16); v += __shfl_down(v, 8);
      v += __shfl_down(v, 4);  v += __shfl_down(v, 2);  v += __shfl_down(v, 1);
      if (lane == 0) red_s[wid * 6 + p] = v;
    }
    __syncthreads();
    if (tid < 6) {
      float sum = 0.f;
#pragma unroll
      for (int w = 0; w < 8; ++w) sum += red_s[w * 6 + tid];
      astore(&z2_buf[pair0 + tid], sum);
    }
  }
  ++nC; bar_arrive(barC, nC, g, tid); bar_wait(barC, nC, tid);

  // ================= final softmax + outputs =================
  if (g < kB) {
    const int b = g;
    if (tid < kS) soft_s[tid] = aload1(&z2_buf[b * kS + tid]);
    __syncthreads();
    float mx = -1e30f;
    for (int i = 0; i < kS; ++i) mx = fmaxf(mx, soft_s[i]);
    float den = 0.f;
    for (int i = 0; i < kS; ++i) den += expf(soft_s[i] - mx);
    __syncthreads();
    if (tid < kS) {
      float al = expf(soft_s[tid] - mx) / den;
      soft_s[tid] = al;
      out[kB * kH + b * kS + tid] = al;  // alpha
    }
    __syncthreads();
    {
      const int h0 = tid;  // NTH == kH
      float acc = 0.f;
      for (int s2 = 0; s2 < kS; ++s2)
        acc += soft_s[s2] * aload1(&sent_hs[(b * kS + s2) * kH + h0]);
      out[b * kH + h0] = acc;  // context
    }
  }
}

extern "C" void kernel_launch(void* const* d_in, const int* in_sizes, int n_in,
                              void* d_out, int out_size, void* d_ws, size_t ws_size,
                              hipStream_t stream) {
  (void)in_sizes; (void)n_in; (void)out_size; (void)ws_size;
  const int* captions = (const int*)d_in[0];
  const int* masks = (const int*)d_in[1];
  const float* embed_W = (const float*)d_in[2];
  const float* w_Wih = (const float*)d_in[3];
  const float* w_Whh = (const float*)d_in[4];
  const float* w_bih = (const float*)d_in[5];
  const float* w_bhh = (const float*)d_in[6];
  const float* s_Wih = (const float*)d_in[7];
  const float* s_Whh = (const float*)d_in[8];
  const float* s_bih = (const float*)d_in[9];
  const float* s_bhh = (const float*)d_in[10];
  const float* wa_Wk = (const float*)d_in[11];
  const float* wa_Wv = (const float*)d_in[12];
  const float* sa_Wk = (const float*)d_in[13];
  const float* sa_Wv = (const float*)d_in[14];
  float* out = (float*)d_out;
  float* ws = (float*)d_ws;

  void* args[] = {&captions, &masks, &embed_W, &w_Wih, &w_Whh, &w_bih, &w_bhh,
                  &s_Wih, &s_Whh, &s_bih, &s_bhh, &wa_Wk, &wa_Wv, &sa_Wk, &sa_Wv,
                  &out, &ws};
  hipLaunchCooperativeKernel((void*)ha_kernel, dim3(NWG), dim3(NTH), args, 0, stream);
}

// Round 4
// 39215.131 us; speedup vs baseline: 1.4080x; 1.4080x over previous
//
#include <hip/hip_runtime.h>
#include <hip/hip_cooperative_groups.h>
#include <math.h>

namespace cg = cooperative_groups;

constexpr int kB = 64, kS = 24, kT = 96, kE = 256, kH = 512, kA = 512;
constexpr int NWG = 256, NTH = 512;

// ws layout (floats)
constexpr int OFF_H   = 0;                          // 2*kB*kH word h (double buf)
constexpr int OFF_SH  = OFF_H + 2 * kB * kH;        // 2*kB*kH sent h (double buf)
constexpr int OFF_HS  = OFF_SH + 2 * kB * kH;       // kB*kT*kH word_hs
constexpr int OFF_Z   = OFF_HS + kB * kT * kH;      // kB*kT
constexpr int OFF_CTX = OFF_Z + kB * kT;            // kB*kH
constexpr int OFF_SHS = OFF_CTX + kB * kH;          // kB*kS*kH
constexpr int OFF_Z2  = OFF_SHS + kB * kS * kH;     // kB*kS
constexpr int OFF_FLG = (OFF_Z2 + kB * kS + 31) & ~31;  // 256 flags, 128B apart

__device__ __forceinline__ float sigmoidf(float x) { return 1.0f / (1.0f + expf(-x)); }
__device__ __forceinline__ float dot4(float4 a, float4 b) {
  return a.x * b.x + a.y * b.y + a.z * b.z + a.w * b.w;
}

// Coherent (LLC) data access for cross-WG data: relaxed agent-scope atomics.
__device__ __forceinline__ float2 aload2(const float* p) {
  unsigned long long u = __hip_atomic_load((const unsigned long long*)p,
                                           __ATOMIC_RELAXED, __HIP_MEMORY_SCOPE_AGENT);
  union { unsigned long long u; float2 f; } cv; cv.u = u;
  return cv.f;
}
__device__ __forceinline__ float aload1(const float* p) {
  return __hip_atomic_load(p, __ATOMIC_RELAXED, __HIP_MEMORY_SCOPE_AGENT);
}
__device__ __forceinline__ void astore(float* p, float v) {
  __hip_atomic_store(p, v, __ATOMIC_RELAXED, __HIP_MEMORY_SCOPE_AGENT);
}

// Broadcast barrier: zero serialized RMWs.
// arrive: each WG release-stores its own flag line (parallel across WGs).
// wait:   threads 0..255 each poll one WG's flag (parallel reads), then syncthreads.
__device__ __forceinline__ void bar_arrive(unsigned* flags, int g, int tid, unsigned n) {
  __syncthreads();  // per-wave vmcnt(0) drain: all our sc1 data stores are in LLC
  if (tid == 0)
    __hip_atomic_store(&flags[g * 32], n, __ATOMIC_RELEASE, __HIP_MEMORY_SCOPE_AGENT);
}
__device__ __forceinline__ void bar_wait(unsigned* flags, int tid, unsigned n) {
  if (tid < NWG) {
    while (__hip_atomic_load(&flags[tid * 32], __ATOMIC_RELAXED,
                             __HIP_MEMORY_SCOPE_AGENT) < n)
      __builtin_amdgcn_s_sleep(2);
  }
  __syncthreads();
}

__global__ __launch_bounds__(NTH) void ha_kernel(
    const int* __restrict__ captions, const int* __restrict__ masks,
    const float* __restrict__ embed_W,
    const float* __restrict__ w_Wih, const float* __restrict__ w_Whh,
    const float* __restrict__ w_bih, const float* __restrict__ w_bhh,
    const float* __restrict__ s_Wih, const float* __restrict__ s_Whh,
    const float* __restrict__ s_bih, const float* __restrict__ s_bhh,
    const float* __restrict__ wa_Wk, const float* __restrict__ wa_Wv,
    const float* __restrict__ sa_Wk, const float* __restrict__ sa_Wv,
    float* __restrict__ out, float* __restrict__ ws) {
  cg::grid_group grid = cg::this_grid();
  const int g = blockIdx.x, tid = threadIdx.x;
  const int jj = tid & 7, bb = tid >> 3;  // 8-way K-split x 64 batch

  float* h_buf = ws + OFF_H;
  float* sh_buf = ws + OFF_SH;
  float* hs_buf = ws + OFF_HS;
  float* z_buf = ws + OFF_Z;
  float* ctx_ws = ws + OFF_CTX;
  float* sent_hs = ws + OFF_SHS;
  float* z2_buf = ws + OFF_Z2;
  unsigned* flags = (unsigned*)(ws + OFF_FLG);

  // LDS ~52 KB
  __shared__ __align__(16) float wih_s[8][260];
  __shared__ __align__(16) float whh_s[8][516];
  __shared__ float bias_s[8];
  __shared__ __align__(16) float smem_u[6192];  // hpart | hpart2 | attn_f (aliased)
  __shared__ float c_s[2][kB], hown_s[2][kB], sc_s[2][kB];
  __shared__ float soft_s[kT], red_s[96];

  // hpart[c][bb][jj]: addr%32 = (8*bb+jj)%32 -> 2 lanes/bank (free per m136)
  float (*hpart)[kB][8] = reinterpret_cast<float (*)[kB][8]>(&smem_u[0]);     // 4096 f
  float (*hpart2)[kB][10] = reinterpret_cast<float (*)[kB][10]>(&smem_u[0]);  // 5120 f
  float* attn_f = &smem_u[0];                                                 // 12x516

  // ---- init (weights via plain cached loads: read-only, L2 stays warm forever) ----
  for (int idx = tid; idx < 8 * kE; idx += NTH) {
    int c = idx >> 8, e = idx & (kE - 1);
    wih_s[c][e] = w_Wih[((c >> 1) * kH + 2 * g + (c & 1)) * kE + e];
  }
  for (int idx = tid; idx < 8 * kH; idx += NTH) {
    int c = idx >> 9, k = idx & (kH - 1);
    whh_s[c][k] = w_Whh[((c >> 1) * kH + 2 * g + (c & 1)) * kH + k];
  }
  if (tid < 8) {
    int row = (tid >> 1) * kH + 2 * g + (tid & 1);
    bias_s[tid] = w_bih[row] + w_bhh[row];
  }
  if (tid < kB) {
    c_s[0][tid] = 0.f; c_s[1][tid] = 0.f;
    hown_s[0][tid] = 0.f; hown_s[1][tid] = 0.f;
    sc_s[0][tid] = 0.f; sc_s[1][tid] = 0.f;
  }
  {
    int idx = g * NTH + tid;  // 131072 threads == 2*(2*kB*kH)
    if (idx < 2 * kB * kH) h_buf[idx] = 0.f;
    else sh_buf[idx - 2 * kB * kH] = 0.f;
  }
  if (g == 0)
    for (int idx = tid; idx < NWG * 32; idx += NTH) flags[idx] = 0u;
  grid.sync();  // one heavy fence: publishes zeros + flags

  float xacc[8];  // x@Wih^T register partials for own slice, prefetched 1 step ahead
  auto prefetch = [&](int s2, int t2) {
    const int cap = captions[(bb * kS + s2) * kT + t2];
    const float4* __restrict__ xrow = (const float4*)(embed_W + (size_t)cap * kE);
#pragma unroll
    for (int c = 0; c < 8; ++c) xacc[c] = 0.f;
#pragma unroll
    for (int i = 0; i < 8; ++i) {
      const int ch = jj + 8 * i;
      float4 xv = xrow[ch];
#pragma unroll
      for (int c = 0; c < 8; ++c)
        xacc[c] += dot4(*(const float4*)&wih_s[c][4 * ch], xv);
    }
  };

  prefetch(0, 0);
  unsigned n = 0;
  int gstep = 0;
  for (int s = 0; s < kS; ++s) {
    // ================= word LSTM: 96 steps, one barrier each =================
    for (int t = 0; t < kT; ++t, ++gstep) {
      const float* hcur = h_buf + (gstep & 1) * kB * kH;
      float* hnxt = h_buf + ((gstep + 1) & 1) * kB * kH;

      // (A) partial dots: thread (jj,bb) covers k-chunks {jj+8i}, 8 owned gate cols
      {
        const float* __restrict__ hrow = hcur + bb * kH;
        float acc[8];
#pragma unroll
        for (int c = 0; c < 8; ++c) acc[c] = xacc[c];
#pragma unroll
        for (int i = 0; i < 16; ++i) {
          const int ch = jj + 8 * i;
          float2 p0 = aload2(hrow + 4 * ch);
          float2 p1 = aload2(hrow + 4 * ch + 2);
#pragma unroll
          for (int c = 0; c < 8; ++c) {
            const float4 w = *(const float4*)&whh_s[c][4 * ch];
            acc[c] += w.x * p0.x + w.y * p0.y + w.z * p1.x + w.w * p1.y;
          }
        }
#pragma unroll
        for (int c = 0; c < 8; ++c) hpart[c][bb][jj] = acc[c];
      }
      __syncthreads();

      // (B) assemble gates, nonlinearity, masked state update, publish
      if (tid < 128) {
        const int p = tid & 1, b = tid >> 1;
        float gate[4];
#pragma unroll
        for (int q = 0; q < 4; ++q) {
          const int c = 2 * q + p;
          float sum = bias_s[c];
#pragma unroll
          for (int j = 0; j < 8; ++j) sum += hpart[c][b][j];
          gate[q] = sum;
        }
        float cold = c_s[p][b];
        float c2 = sigmoidf(gate[1]) * cold + sigmoidf(gate[0]) * tanhf(gate[2]);
        float h2 = sigmoidf(gate[3]) * tanhf(c2);
        const int m = masks[(b * kS + s) * kT + t];
        float cn = m ? c2 : cold;
        float hn = m ? h2 : hown_s[p][b];
        c_s[p][b] = cn;
        hown_s[p][b] = hn;
        const int col = 2 * g + p;
        astore(&hnxt[b * kH + col], hn);
        astore(&hs_buf[(b * kT + t) * kH + col], m ? h2 : 0.f);
      }

      ++n;
      bar_arrive(flags, g, tid, n);
      if (t < kT - 1) prefetch(s, t + 1);  // hidden in the barrier window
      bar_wait(flags, tid, n);
    }

    // ================= word attention: z[b,t] =================
    {
      const int ab = g >> 2, at0 = (g & 3) * 24;
      for (int half = 0; half < 2; ++half) {
        const int tb = at0 + half * 12;
        for (int idx = tid; idx < 12 * 256; idx += NTH) {
          int pp = idx >> 8, hh2 = (idx & 255) * 2;
          float2 v = aload2(&hs_buf[(ab * kT + tb + pp) * kH + hh2]);
          *(float2*)&attn_f[pp * 516 + hh2] = v;
        }
        __syncthreads();
        const int aa = tid;  // NTH == kA
        float dacc[12];
#pragma unroll
        for (int p = 0; p < 12; ++p) dacc[p] = 0.f;
        const float4* __restrict__ wk = (const float4*)(wa_Wk + aa * kH);
        for (int k = 0; k < kH / 4; ++k) {
          float4 w = wk[k];
#pragma unroll
          for (int p = 0; p < 12; ++p)
            dacc[p] += dot4(w, *(const float4*)&attn_f[p * 516 + k * 4]);
        }
        const float wv = wa_Wv[aa];
        const int lane = tid & 63, wid = tid >> 6;
#pragma unroll
        for (int p = 0; p < 12; ++p) {
          float v = wv * tanhf(dacc[p]);
          v += __shfl_down(v, 32); v += __shfl_down(v, 16); v += __shfl_down(v, 8);
          v += __shfl_down(v, 4);  v += __shfl_down(v, 2);  v += __shfl_down(v, 1);
          if (lane == 0) red_s[wid * 12 + p] = v;
        }
        __syncthreads();
        if (tid < 12) {
          float sum = 0.f;
#pragma unroll
          for (int w = 0; w < 8; ++w) sum += red_s[w * 12 + tid];
          astore(&z_buf[ab * kT + tb + tid], sum);
        }
        __syncthreads();
      }
    }
    ++n; bar_arrive(flags, g, tid, n); bar_wait(flags, tid, n);

    // ================= softmax over T + ctx =================
    if (g < kB) {
      const int b = g;
      if (tid < kT) soft_s[tid] = aload1(&z_buf[b * kT + tid]);
      __syncthreads();
      float mx = -1e30f;
      for (int i = 0; i < kT; ++i) mx = fmaxf(mx, soft_s[i]);
      float den = 0.f;
      for (int i = 0; i < kT; ++i) den += expf(soft_s[i] - mx);
      __syncthreads();
      if (tid < kT) soft_s[tid] = expf(soft_s[tid] - mx) / den;
      __syncthreads();
      {
        const int h0 = tid;  // NTH == kH
        float a0 = 0.f, a1 = 0.f, a2 = 0.f, a3 = 0.f;
        for (int tt = 0; tt < kT; tt += 4) {
          a0 += soft_s[tt + 0] * aload1(&hs_buf[(b * kT + tt + 0) * kH + h0]);
          a1 += soft_s[tt + 1] * aload1(&hs_buf[(b * kT + tt + 1) * kH + h0]);
          a2 += soft_s[tt + 2] * aload1(&hs_buf[(b * kT + tt + 2) * kH + h0]);
          a3 += soft_s[tt + 3] * aload1(&hs_buf[(b * kT + tt + 3) * kH + h0]);
        }
        astore(&ctx_ws[b * kH + h0], (a0 + a1) + (a2 + a3));
      }
    }
    ++n; bar_arrive(flags, g, tid, n); bar_wait(flags, tid, n);

    // ================= sentence LSTM step =================
    {
      const float* shc = sh_buf + (s & 1) * kB * kH;
      float* shn = sh_buf + ((s + 1) & 1) * kB * kH;
      float acc[8];
#pragma unroll
      for (int c = 0; c < 8; ++c) acc[c] = 0.f;
      for (int i = 0; i < 16; ++i) {
        const int ch = jj + 8 * i;
        float2 x0 = aload2(ctx_ws + bb * kH + 4 * ch);
        float2 x1 = aload2(ctx_ws + bb * kH + 4 * ch + 2);
        float2 h0 = aload2(shc + bb * kH + 4 * ch);
        float2 h1 = aload2(shc + bb * kH + 4 * ch + 2);
#pragma unroll
        for (int c = 0; c < 8; ++c) {
          const int row = (c >> 1) * kH + 2 * g + (c & 1);
          float4 wi = *(const float4*)(s_Wih + row * kH + 4 * ch);
          float4 wh = *(const float4*)(s_Whh + row * kH + 4 * ch);
          acc[c] += wi.x * x0.x + wi.y * x0.y + wi.z * x1.x + wi.w * x1.y +
                    wh.x * h0.x + wh.y * h0.y + wh.z * h1.x + wh.w * h1.y;
        }
      }
#pragma unroll
      for (int c = 0; c < 8; ++c) hpart2[c][bb][jj] = acc[c];
      __syncthreads();
      if (tid < 128) {
        const int p = tid & 1, b = tid >> 1;
        float gate[4];
#pragma unroll
        for (int q = 0; q < 4; ++q) {
          const int c = 2 * q + p;
          const int row = q * kH + 2 * g + p;
          float sum = s_bih[row] + s_bhh[row];
#pragma unroll
          for (int j = 0; j < 8; ++j) sum += hpart2[c][b][j];
          gate[q] = sum;
        }
        float c2 = sigmoidf(gate[1]) * sc_s[p][b] + sigmoidf(gate[0]) * tanhf(gate[2]);
        float h2 = sigmoidf(gate[3]) * tanhf(c2);
        sc_s[p][b] = c2;
        const int col = 2 * g + p;
        astore(&shn[b * kH + col], h2);
        astore(&sent_hs[(b * kS + s) * kH + col], h2);
      }
    }
    ++n; bar_arrive(flags, g, tid, n);
    if (s < kS - 1) prefetch(s + 1, 0);  // hidden in the barrier window
    bar_wait(flags, tid, n);
  }

  // ================= final attention over S =================
  {
    const int pair0 = g * 6;  // 1536 (b,s) pairs / 256 WGs
    for (int idx = tid; idx < 6 * 256; idx += NTH) {
      int pp = idx >> 8, hh2 = (idx & 255) * 2;
      float2 v = aload2(&sent_hs[(pair0 + pp) * kH + hh2]);
      *(float2*)&attn_f[pp * 516 + hh2] = v;
    }
    __syncthreads();
    const int aa = tid;
    float dacc[6];
#pragma unroll
    for (int p = 0; p < 6; ++p) dacc[p] = 0.f;
    const float4* __restrict__ wk = (const float4*)(sa_Wk + aa * kH);
    for (int k = 0; k < kH / 4; ++k) {
      float4 w = wk[k];
#pragma unroll
      for (int p = 0; p < 6; ++p)
        dacc[p] += dot4(w, *(const float4*)&attn_f[p * 516 + k * 4]);
    }
    const float wv = sa_Wv[aa];
    const int lane = tid & 63, wid = tid >> 6;
#pragma unroll
    for (int p = 0; p < 6; ++p) {
      float v = wv * tanhf(dacc[p]);
      v += __shfl_down(v, 32); v += __shfl_down(v, 16); v += __shfl_down(v, 8);
      v += __shfl_down(v, 4);  v += __shfl_down(v, 2);  v += __shfl_down(v, 1);
      if (lane == 0) red_s[wid * 6 + p] = v;
    }
    __syncthreads();
    if (tid < 6) {
      float sum = 0.f;
#pragma unroll
      for (int w = 0; w < 8; ++w) sum += red_s[w * 6 + tid];
      astore(&z2_buf[pair0 + tid], sum);
    }
  }
  ++n; bar_arrive(flags, g, tid, n); bar_wait(flags, tid, n);

  // ================= final softmax + outputs =================
  if (g < kB) {
    const int b = g;
    if (tid < kS) soft_s[tid] = aload1(&z2_buf[b * kS + tid]);
    __syncthreads();
    float mx = -1e30f;
    for (int i = 0; i < kS; ++i) mx = fmaxf(mx, soft_s[i]);
    float den = 0.f;
    for (int i = 0; i < kS; ++i) den += expf(soft_s[i] - mx);
    __syncthreads();
    if (tid < kS) {
      float al = expf(soft_s[tid] - mx) / den;
      soft_s[tid] = al;
      out[kB * kH + b * kS + tid] = al;  // alpha
    }
    __syncthreads();
    {
      const int h0 = tid;  // NTH == kH
      float acc = 0.f;
      for (int s2 = 0; s2 < kS; ++s2)
        acc += soft_s[s2] * aload1(&sent_hs[(b * kS + s2) * kH + h0]);
      out[b * kH + h0] = acc;  // context
    }
  }
}

extern "C" void kernel_launch(void* const* d_in, const int* in_sizes, int n_in,
                              void* d_out, int out_size, void* d_ws, size_t ws_size,
                              hipStream_t stream) {
  (void)in_sizes; (void)n_in; (void)out_size; (void)ws_size;
  const int* captions = (const int*)d_in[0];
  const int* masks = (const int*)d_in[1];
  const float* embed_W = (const float*)d_in[2];
  const float* w_Wih = (const float*)d_in[3];
  const float* w_Whh = (const float*)d_in[4];
  const float* w_bih = (const float*)d_in[5];
  const float* w_bhh = (const float*)d_in[6];
  const float* s_Wih = (const float*)d_in[7];
  const float* s_Whh = (const float*)d_in[8];
  const float* s_bih = (const float*)d_in[9];
  const float* s_bhh = (const float*)d_in[10];
  const float* wa_Wk = (const float*)d_in[11];
  const float* wa_Wv = (const float*)d_in[12];
  const float* sa_Wk = (const float*)d_in[13];
  const float* sa_Wv = (const float*)d_in[14];
  float* out = (float*)d_out;
  float* ws = (float*)d_ws;

  void* args[] = {&captions, &masks, &embed_W, &w_Wih, &w_Whh, &w_bih, &w_bhh,
                  &s_Wih, &s_Whh, &s_bih, &s_bhh, &wa_Wk, &wa_Wv, &sa_Wk, &sa_Wv,
                  &out, &ws};
  hipLaunchCooperativeKernel((void*)ha_kernel, dim3(NWG), dim3(NTH), args, 0, stream);
}

// Round 5
// 35288.959 us; speedup vs baseline: 1.5646x; 1.1113x over previous
//
#include <hip/hip_runtime.h>
#include <hip/hip_cooperative_groups.h>
#include <math.h>

namespace cg = cooperative_groups;

constexpr int kB = 64, kS = 24, kT = 96, kE = 256, kH = 512, kA = 512;
constexpr int NWG = 256, NTH = 512;

// ws layout (floats)
constexpr int OFF_H   = 0;                          // 2*kB*kH word h (double buf)
constexpr int OFF_SH  = OFF_H + 2 * kB * kH;        // 2*kB*kH sent h (double buf)
constexpr int OFF_HS  = OFF_SH + 2 * kB * kH;       // kB*kT*kH word_hs
constexpr int OFF_Z   = OFF_HS + kB * kT * kH;      // kB*kT
constexpr int OFF_CTX = OFF_Z + kB * kT;            // kB*kH
constexpr int OFF_SHS = OFF_CTX + kB * kH;          // kB*kS*kH
constexpr int OFF_Z2  = OFF_SHS + kB * kS * kH;     // kB*kS
constexpr int OFF_FLG = (OFF_Z2 + kB * kS + 31) & ~31;  // 256 flags, 128B apart

__device__ __forceinline__ float sigmoidf(float x) { return 1.0f / (1.0f + expf(-x)); }
__device__ __forceinline__ float dot4(float4 a, float4 b) {
  return a.x * b.x + a.y * b.y + a.z * b.z + a.w * b.w;
}

// Coherent (LLC) data access for cross-WG data: relaxed agent-scope atomics.
__device__ __forceinline__ float2 aload2(const float* p) {
  unsigned long long u = __hip_atomic_load((const unsigned long long*)p,
                                           __ATOMIC_RELAXED, __HIP_MEMORY_SCOPE_AGENT);
  union { unsigned long long u; float2 f; } cv; cv.u = u;
  return cv.f;
}
__device__ __forceinline__ float aload1(const float* p) {
  return __hip_atomic_load(p, __ATOMIC_RELAXED, __HIP_MEMORY_SCOPE_AGENT);
}
__device__ __forceinline__ void astore(float* p, float v) {
  __hip_atomic_store(p, v, __ATOMIC_RELAXED, __HIP_MEMORY_SCOPE_AGENT);
}

// Broadcast barrier, fence-free.
// arrive: __syncthreads() drains each wave's vmcnt(0) before s_barrier, so every
//         sc1 data store of this WG is already complete at LLC; then a RELAXED
//         flag store (no release -> no L2 writeback/cache maintenance).
// wait:   64 threads poll 4 flags each (relaxed, LLC), then __syncthreads.
__device__ __forceinline__ void bar_arrive(unsigned* flags, int g, int tid, unsigned n) {
  __syncthreads();
  if (tid == 0)
    __hip_atomic_store(&flags[g * 32], n, __ATOMIC_RELAXED, __HIP_MEMORY_SCOPE_AGENT);
}
__device__ __forceinline__ void bar_wait(unsigned* flags, int tid, unsigned n) {
  if (tid < 64) {
    const int base = tid * 4;
#pragma unroll
    for (int k = 0; k < 4; ++k) {
      while (__hip_atomic_load(&flags[(base + k) * 32], __ATOMIC_RELAXED,
                               __HIP_MEMORY_SCOPE_AGENT) < n)
        __builtin_amdgcn_s_sleep(1);
    }
  }
  __syncthreads();
}

__global__ __launch_bounds__(NTH) void ha_kernel(
    const int* __restrict__ captions, const int* __restrict__ masks,
    const float* __restrict__ embed_W,
    const float* __restrict__ w_Wih, const float* __restrict__ w_Whh,
    const float* __restrict__ w_bih, const float* __restrict__ w_bhh,
    const float* __restrict__ s_Wih, const float* __restrict__ s_Whh,
    const float* __restrict__ s_bih, const float* __restrict__ s_bhh,
    const float* __restrict__ wa_Wk, const float* __restrict__ wa_Wv,
    const float* __restrict__ sa_Wk, const float* __restrict__ sa_Wv,
    float* __restrict__ out, float* __restrict__ ws) {
  cg::grid_group grid = cg::this_grid();
  const int g = blockIdx.x, tid = threadIdx.x;
  const int jj = tid & 7, bb = tid >> 3;  // 8-way K-split x 64 batch

  float* h_buf = ws + OFF_H;
  float* sh_buf = ws + OFF_SH;
  float* hs_buf = ws + OFF_HS;
  float* z_buf = ws + OFF_Z;
  float* ctx_ws = ws + OFF_CTX;
  float* sent_hs = ws + OFF_SHS;
  float* z2_buf = ws + OFF_Z2;
  unsigned* flags = (unsigned*)(ws + OFF_FLG);

  // LDS ~52 KB
  __shared__ __align__(16) float wih_s[8][260];
  __shared__ __align__(16) float whh_s[8][516];
  __shared__ float bias_s[8];
  __shared__ __align__(16) float smem_u[6192];  // hpart | hpart2 | attn_f (aliased)
  __shared__ float c_s[2][kB], hown_s[2][kB], sc_s[2][kB];
  __shared__ float soft_s[kT], red_s[96];

  // hpart[c][bb][jj]: addr%32 = (8*bb+jj)%32 -> 2 lanes/bank (free per m136)
  float (*hpart)[kB][8] = reinterpret_cast<float (*)[kB][8]>(&smem_u[0]);     // 4096 f
  float (*hpart2)[kB][10] = reinterpret_cast<float (*)[kB][10]>(&smem_u[0]);  // 5120 f
  float* attn_f = &smem_u[0];                                                 // 12x516

  // ---- init (weights via plain cached loads: read-only, L2 stays warm forever) ----
  for (int idx = tid; idx < 8 * kE; idx += NTH) {
    int c = idx >> 8, e = idx & (kE - 1);
    wih_s[c][e] = w_Wih[((c >> 1) * kH + 2 * g + (c & 1)) * kE + e];
  }
  for (int idx = tid; idx < 8 * kH; idx += NTH) {
    int c = idx >> 9, k = idx & (kH - 1);
    whh_s[c][k] = w_Whh[((c >> 1) * kH + 2 * g + (c & 1)) * kH + k];
  }
  if (tid < 8) {
    int row = (tid >> 1) * kH + 2 * g + (tid & 1);
    bias_s[tid] = w_bih[row] + w_bhh[row];
  }
  if (tid < kB) {
    c_s[0][tid] = 0.f; c_s[1][tid] = 0.f;
    hown_s[0][tid] = 0.f; hown_s[1][tid] = 0.f;
    sc_s[0][tid] = 0.f; sc_s[1][tid] = 0.f;
  }
  {
    int idx = g * NTH + tid;  // 131072 threads == 2*(2*kB*kH)
    if (idx < 2 * kB * kH) h_buf[idx] = 0.f;
    else sh_buf[idx - 2 * kB * kH] = 0.f;
  }
  if (g == 0)
    for (int idx = tid; idx < NWG * 32; idx += NTH) flags[idx] = 0u;
  grid.sync();  // one heavy fence: publishes zeros + flags

  float xacc[8];  // x@Wih^T register partials for own slice, prefetched 1 step ahead
  auto prefetch = [&](int s2, int t2) {
    const int cap = captions[(bb * kS + s2) * kT + t2];
    const float4* __restrict__ xrow = (const float4*)(embed_W + (size_t)cap * kE);
#pragma unroll
    for (int c = 0; c < 8; ++c) xacc[c] = 0.f;
#pragma unroll
    for (int i = 0; i < 8; ++i) {
      const int ch = jj + 8 * i;
      float4 xv = xrow[ch];
#pragma unroll
      for (int c = 0; c < 8; ++c)
        xacc[c] += dot4(*(const float4*)&wih_s[c][4 * ch], xv);
    }
  };

  prefetch(0, 0);
  unsigned n = 0;
  int gstep = 0;
  for (int s = 0; s < kS; ++s) {
    // ================= word LSTM: 96 steps, one barrier each =================
    for (int t = 0; t < kT; ++t, ++gstep) {
      const float* hcur = h_buf + (gstep & 1) * kB * kH;
      float* hnxt = h_buf + ((gstep + 1) & 1) * kB * kH;

      // (A) partial dots: thread (jj,bb) covers k-chunks {jj+8i}, 8 owned gate cols
      {
        const float* __restrict__ hrow = hcur + bb * kH;
        float acc[8];
#pragma unroll
        for (int c = 0; c < 8; ++c) acc[c] = xacc[c];
#pragma unroll
        for (int i = 0; i < 16; ++i) {
          const int ch = jj + 8 * i;
          float2 p0 = aload2(hrow + 4 * ch);
          float2 p1 = aload2(hrow + 4 * ch + 2);
#pragma unroll
          for (int c = 0; c < 8; ++c) {
            const float4 w = *(const float4*)&whh_s[c][4 * ch];
            acc[c] += w.x * p0.x + w.y * p0.y + w.z * p1.x + w.w * p1.y;
          }
        }
#pragma unroll
        for (int c = 0; c < 8; ++c) hpart[c][bb][jj] = acc[c];
      }
      __syncthreads();

      // (B) assemble gates, nonlinearity, masked state update, publish
      if (tid < 128) {
        const int p = tid & 1, b = tid >> 1;
        float gate[4];
#pragma unroll
        for (int q = 0; q < 4; ++q) {
          const int c = 2 * q + p;
          float sum = bias_s[c];
#pragma unroll
          for (int j = 0; j < 8; ++j) sum += hpart[c][b][j];
          gate[q] = sum;
        }
        float cold = c_s[p][b];
        float c2 = sigmoidf(gate[1]) * cold + sigmoidf(gate[0]) * tanhf(gate[2]);
        float h2 = sigmoidf(gate[3]) * tanhf(c2);
        const int m = masks[(b * kS + s) * kT + t];
        float cn = m ? c2 : cold;
        float hn = m ? h2 : hown_s[p][b];
        c_s[p][b] = cn;
        hown_s[p][b] = hn;
        const int col = 2 * g + p;
        astore(&hnxt[b * kH + col], hn);
        astore(&hs_buf[(b * kT + t) * kH + col], m ? h2 : 0.f);
      }

      ++n;
      bar_arrive(flags, g, tid, n);
      if (t < kT - 1) prefetch(s, t + 1);  // hidden in the barrier window
      bar_wait(flags, tid, n);
    }

    // ================= word attention: z[b,t] =================
    {
      const int ab = g >> 2, at0 = (g & 3) * 24;
      for (int half = 0; half < 2; ++half) {
        const int tb = at0 + half * 12;
        for (int idx = tid; idx < 12 * 256; idx += NTH) {
          int pp = idx >> 8, hh2 = (idx & 255) * 2;
          float2 v = aload2(&hs_buf[(ab * kT + tb + pp) * kH + hh2]);
          *(float2*)&attn_f[pp * 516 + hh2] = v;
        }
        __syncthreads();
        const int aa = tid;  // NTH == kA
        float dacc[12];
#pragma unroll
        for (int p = 0; p < 12; ++p) dacc[p] = 0.f;
        const float4* __restrict__ wk = (const float4*)(wa_Wk + aa * kH);
        for (int k = 0; k < kH / 4; ++k) {
          float4 w = wk[k];
#pragma unroll
          for (int p = 0; p < 12; ++p)
            dacc[p] += dot4(w, *(const float4*)&attn_f[p * 516 + k * 4]);
        }
        const float wv = wa_Wv[aa];
        const int lane = tid & 63, wid = tid >> 6;
#pragma unroll
        for (int p = 0; p < 12; ++p) {
          float v = wv * tanhf(dacc[p]);
          v += __shfl_down(v, 32); v += __shfl_down(v, 16); v += __shfl_down(v, 8);
          v += __shfl_down(v, 4);  v += __shfl_down(v, 2);  v += __shfl_down(v, 1);
          if (lane == 0) red_s[wid * 12 + p] = v;
        }
        __syncthreads();
        if (tid < 12) {
          float sum = 0.f;
#pragma unroll
          for (int w = 0; w < 8; ++w) sum += red_s[w * 12 + tid];
          astore(&z_buf[ab * kT + tb + tid], sum);
        }
        __syncthreads();
      }
    }
    ++n; bar_arrive(flags, g, tid, n); bar_wait(flags, tid, n);

    // ================= softmax over T + ctx =================
    if (g < kB) {
      const int b = g;
      if (tid < kT) soft_s[tid] = aload1(&z_buf[b * kT + tid]);
      __syncthreads();
      float mx = -1e30f;
      for (int i = 0; i < kT; ++i) mx = fmaxf(mx, soft_s[i]);
      float den = 0.f;
      for (int i = 0; i < kT; ++i) den += expf(soft_s[i] - mx);
      __syncthreads();
      if (tid < kT) soft_s[tid] = expf(soft_s[tid] - mx) / den;
      __syncthreads();
      {
        const int h0 = tid;  // NTH == kH
        float a0 = 0.f, a1 = 0.f, a2 = 0.f, a3 = 0.f;
        for (int tt = 0; tt < kT; tt += 4) {
          a0 += soft_s[tt + 0] * aload1(&hs_buf[(b * kT + tt + 0) * kH + h0]);
          a1 += soft_s[tt + 1] * aload1(&hs_buf[(b * kT + tt + 1) * kH + h0]);
          a2 += soft_s[tt + 2] * aload1(&hs_buf[(b * kT + tt + 2) * kH + h0]);
          a3 += soft_s[tt + 3] * aload1(&hs_buf[(b * kT + tt + 3) * kH + h0]);
        }
        astore(&ctx_ws[b * kH + h0], (a0 + a1) + (a2 + a3));
      }
    }
    ++n; bar_arrive(flags, g, tid, n); bar_wait(flags, tid, n);

    // ================= sentence LSTM step =================
    {
      const float* shc = sh_buf + (s & 1) * kB * kH;
      float* shn = sh_buf + ((s + 1) & 1) * kB * kH;
      float acc[8];
#pragma unroll
      for (int c = 0; c < 8; ++c) acc[c] = 0.f;
      for (int i = 0; i < 16; ++i) {
        const int ch = jj + 8 * i;
        float2 x0 = aload2(ctx_ws + bb * kH + 4 * ch);
        float2 x1 = aload2(ctx_ws + bb * kH + 4 * ch + 2);
        float2 h0 = aload2(shc + bb * kH + 4 * ch);
        float2 h1 = aload2(shc + bb * kH + 4 * ch + 2);
#pragma unroll
        for (int c = 0; c < 8; ++c) {
          const int row = (c >> 1) * kH + 2 * g + (c & 1);
          float4 wi = *(const float4*)(s_Wih + row * kH + 4 * ch);
          float4 wh = *(const float4*)(s_Whh + row * kH + 4 * ch);
          acc[c] += wi.x * x0.x + wi.y * x0.y + wi.z * x1.x + wi.w * x1.y +
                    wh.x * h0.x + wh.y * h0.y + wh.z * h1.x + wh.w * h1.y;
        }
      }
#pragma unroll
      for (int c = 0; c < 8; ++c) hpart2[c][bb][jj] = acc[c];
      __syncthreads();
      if (tid < 128) {
        const int p = tid & 1, b = tid >> 1;
        float gate[4];
#pragma unroll
        for (int q = 0; q < 4; ++q) {
          const int c = 2 * q + p;
          const int row = q * kH + 2 * g + p;
          float sum = s_bih[row] + s_bhh[row];
#pragma unroll
          for (int j = 0; j < 8; ++j) sum += hpart2[c][b][j];
          gate[q] = sum;
        }
        float c2 = sigmoidf(gate[1]) * sc_s[p][b] + sigmoidf(gate[0]) * tanhf(gate[2]);
        float h2 = sigmoidf(gate[3]) * tanhf(c2);
        sc_s[p][b] = c2;
        const int col = 2 * g + p;
        astore(&shn[b * kH + col], h2);
        astore(&sent_hs[(b * kS + s) * kH + col], h2);
      }
    }
    ++n; bar_arrive(flags, g, tid, n);
    if (s < kS - 1) prefetch(s + 1, 0);  // hidden in the barrier window
    bar_wait(flags, tid, n);
  }

  // ================= final attention over S =================
  {
    const int pair0 = g * 6;  // 1536 (b,s) pairs / 256 WGs
    for (int idx = tid; idx < 6 * 256; idx += NTH) {
      int pp = idx >> 8, hh2 = (idx & 255) * 2;
      float2 v = aload2(&sent_hs[(pair0 + pp) * kH + hh2]);
      *(float2*)&attn_f[pp * 516 + hh2] = v;
    }
    __syncthreads();
    const int aa = tid;
    float dacc[6];
#pragma unroll
    for (int p = 0; p < 6; ++p) dacc[p] = 0.f;
    const float4* __restrict__ wk = (const float4*)(sa_Wk + aa * kH);
    for (int k = 0; k < kH / 4; ++k) {
      float4 w = wk[k];
#pragma unroll
      for (int p = 0; p < 6; ++p)
        dacc[p] += dot4(w, *(const float4*)&attn_f[p * 516 + k * 4]);
    }
    const float wv = sa_Wv[aa];
    const int lane = tid & 63, wid = tid >> 6;
#pragma unroll
    for (int p = 0; p < 6; ++p) {
      float v = wv * tanhf(dacc[p]);
      v += __shfl_down(v, 32); v += __shfl_down(v, 16); v += __shfl_down(v, 8);
      v += __shfl_down(v, 4);  v += __shfl_down(v, 2);  v += __shfl_down(v, 1);
      if (lane == 0) red_s[wid * 6 + p] = v;
    }
    __syncthreads();
    if (tid < 6) {
      float sum = 0.f;
#pragma unroll
      for (int w = 0; w < 8; ++w) sum += red_s[w * 6 + tid];
      astore(&z2_buf[pair0 + tid], sum);
    }
  }
  ++n; bar_arrive(flags, g, tid, n); bar_wait(flags, tid, n);

  // ================= final softmax + outputs =================
  if (g < kB) {
    const int b = g;
    if (tid < kS) soft_s[tid] = aload1(&z2_buf[b * kS + tid]);
    __syncthreads();
    float mx = -1e30f;
    for (int i = 0; i < kS; ++i) mx = fmaxf(mx, soft_s[i]);
    float den = 0.f;
    for (int i = 0; i < kS; ++i) den += expf(soft_s[i] - mx);
    __syncthreads();
    if (tid < kS) {
      float al = expf(soft_s[tid] - mx) / den;
      soft_s[tid] = al;
      out[kB * kH + b * kS + tid] = al;  // alpha
    }
    __syncthreads();
    {
      const int h0 = tid;  // NTH == kH
      float acc = 0.f;
      for (int s2 = 0; s2 < kS; ++s2)
        acc += soft_s[s2] * aload1(&sent_hs[(b * kS + s2) * kH + h0]);
      out[b * kH + h0] = acc;  // context
    }
  }
}

extern "C" void kernel_launch(void* const* d_in, const int* in_sizes, int n_in,
                              void* d_out, int out_size, void* d_ws, size_t ws_size,
                              hipStream_t stream) {
  (void)in_sizes; (void)n_in; (void)out_size; (void)ws_size;
  const int* captions = (const int*)d_in[0];
  const int* masks = (const int*)d_in[1];
  const float* embed_W = (const float*)d_in[2];
  const float* w_Wih = (const float*)d_in[3];
  const float* w_Whh = (const float*)d_in[4];
  const float* w_bih = (const float*)d_in[5];
  const float* w_bhh = (const float*)d_in[6];
  const float* s_Wih = (const float*)d_in[7];
  const float* s_Whh = (const float*)d_in[8];
  const float* s_bih = (const float*)d_in[9];
  const float* s_bhh = (const float*)d_in[10];
  const float* wa_Wk = (const float*)d_in[11];
  const float* wa_Wv = (const float*)d_in[12];
  const float* sa_Wk = (const float*)d_in[13];
  const float* sa_Wv = (const float*)d_in[14];
  float* out = (float*)d_out;
  float* ws = (float*)d_ws;

  void* args[] = {&captions, &masks, &embed_W, &w_Wih, &w_Whh, &w_bih, &w_bhh,
                  &s_Wih, &s_Whh, &s_bih, &s_bhh, &wa_Wk, &wa_Wv, &sa_Wk, &sa_Wv,
                  &out, &ws};
  hipLaunchCooperativeKernel((void*)ha_kernel, dim3(NWG), dim3(NTH), args, 0, stream);
}